// Round 14
// baseline (272.809 us; speedup 1.0000x reference)
//
#include <hip/hip_runtime.h>

#define NBATCH 32
#define SEQ    2048
#define NU     512
#define ASTR   36   // A LDS row stride in shorts (72 B)

typedef __attribute__((ext_vector_type(8)))  short bf16x8;
typedef __attribute__((ext_vector_type(16))) float f32x16;

__device__ __forceinline__ short bf16_rne(float f) {
  union { float f; unsigned u; } v; v.f = f;
  unsigned r = v.u + 0x7fffu + ((v.u >> 16) & 1u);
  return (short)(r >> 16);
}

// pack bf16(lo), bf16(hi) (truncation) into one u32 via a single v_perm_b32
__device__ __forceinline__ unsigned pk2(float lo, float hi) {
  return __builtin_amdgcn_perm(__float_as_uint(hi), __float_as_uint(lo), 0x07060302u);
}

__device__ __forceinline__ float fast_tanh(float x) {
  float ax = __builtin_fabsf(x);
  float t  = __expf(-2.0f * ax);
  float r  = (1.0f - t) / (1.0f + t);
  return x < 0.0f ? -r : r;
}

// ---------- fused prep ----------
// blocks 0..127: Wfrag packing — fragment (g,s), lane l, elem j:
//   Wfrag[((g*32+s)*64 + l)*8 + j] = bf16(W[s*16 + (l>>5)*8 + j][g*32 + (l&31)])
//   -> in-kernel, lane l's B-operand for (col-tile g, k-step s) is ONE dwordx4 at
//      lane-contiguous address: perfectly coalesced, L2-resident, no LDS needed.
// blocks 128..191: first[b][u] = s_prev[b]@U + U_bias + W_bias
__global__ __launch_bounds__(256) void prep_all(const float* __restrict__ W,
                                                const float* __restrict__ sp,
                                                const float* __restrict__ U,
                                                const float* __restrict__ Ub,
                                                const float* __restrict__ Wb,
                                                short* __restrict__ Wfrag,
                                                float* __restrict__ first) {
  __shared__ float srow[NU];
  if (blockIdx.x < 128) {
    int idx = blockIdx.x * 256 + threadIdx.x;   // 0..32767 fragments-lanes
    int l = idx & 63;
    int s = (idx >> 6) & 31;
    int g = idx >> 11;                          // 0..15
    int colg = g * 32 + (l & 31);
    int kbase = s * 16 + ((l >> 5) << 3);
    #pragma unroll
    for (int j = 0; j < 8; ++j)
      Wfrag[(size_t)idx * 8 + j] = bf16_rne(W[(size_t)(kbase + j) * NU + colg]);
  } else {
    int blk = blockIdx.x - 128;                 // 0..63
    int b = blk >> 1, half = blk & 1, t = threadIdx.x;
    srow[t]       = sp[b * NU + t];
    srow[t + 256] = sp[b * NU + t + 256];
    __syncthreads();
    int col = half * 256 + t;
    float acc = Ub[col] + Wb[col];
    #pragma unroll 8
    for (int k = 0; k < NU; ++k) acc += srow[k] * U[(size_t)k * NU + col];
    first[b * NU + col] = acc;
  }
}

// ---------- main: R13 structure, B direct-from-L2 fragments, A-only LDS, setprio ----------
// 256 rows x 128 cols per block, 8 waves (4 row x 2 col), wave tile 64x64,
// acc[2][2] f32x16 = 64 f32. h depth-2 reg prefetch -> cvt -> A LDS dbuf;
// B fragments loaded straight from global (L2) 2 iterations ahead into named regs.
// Barriers are lgkm-only (A ds_writes); setprio(1) wraps each MFMA cluster.
__global__ __launch_bounds__(512, 4) void attn_main(
    const float* __restrict__ h,      // (65536, 512) fp32
    const short* __restrict__ Wfrag,  // pre-packed B fragments (512 KB)
    const float* __restrict__ first,  // (B, 512) incl. U_bias + W_bias
    const float* __restrict__ V,      // (512)
    float* __restrict__ s0)           // (65536) score accumulator (pre-zeroed)
{
  __shared__ short Alds[2][256 * ASTR];   // 18.4 KB each (A only)
  __shared__ float scores_lds[256];

  const int tid  = threadIdx.x;
  const int lane = tid & 63;
  const int w    = tid >> 6;
  const int wr   = w >> 1, wc = w & 1;
  const int l31  = lane & 31, hi = lane >> 5;

  // XCD-aware remap: 4 col-quarters of a row-panel adjacent on one XCD
  const int bid = blockIdx.x;
  const int lb  = (bid & 7) * 128 + (bid >> 3);    // grid 1024 = 8*128, bijective
  const int panel = lb >> 2, q = lb & 3;
  const int rowbase = panel * 256;
  const int b = panel >> 3;

  // ---- A staging addresses
  const int arow  = tid >> 1;
  const int ahalf = tid & 1;
  const float* hA = h + (size_t)(rowbase + arow) * NU + ahalf * 16;
  const int awr   = arow * ASTR + ahalf * 16;

  // ---- B fragment pointers (ct = 0/1 -> g0, g0+1)
  const int g0 = q * 4 + wc * 2;
  const bf16x8* wf0 = reinterpret_cast<const bf16x8*>(Wfrag) + (size_t)g0 * 32 * 64 + lane;
  const bf16x8* wf1 = wf0 + 32 * 64;

  // ---- A compute-read bases (shorts)
  const int rA0 = (wr * 64 + l31) * ASTR + hi * 8;
  const int rA1 = rA0 + 32 * ASTR;

  f32x16 acc[2][2];
  #pragma unroll
  for (int rt = 0; rt < 2; ++rt)
    #pragma unroll
    for (int ct = 0; ct < 2; ++ct)
      #pragma unroll
      for (int r = 0; r < 16; ++r) acc[rt][ct][r] = 0.f;

  float4 ha0, ha1, ha2, ha3;        // h slot a
  float4 hb0, hb1, hb2, hb3;        // h slot b
  bf16x8 fa00, fa01, fa10, fa11;    // B frags, even tiles: [ct][ks]
  bf16x8 fb00, fb01, fb10, fb11;    // B frags, odd tiles

  #define LOAD_H(V0, V1, V2, V3, ktn)                                       \
    {                                                                       \
      const float* p = hA + (ktn) * 32;                                     \
      V0 = *reinterpret_cast<const float4*>(p + 0);                         \
      V1 = *reinterpret_cast<const float4*>(p + 4);                         \
      V2 = *reinterpret_cast<const float4*>(p + 8);                         \
      V3 = *reinterpret_cast<const float4*>(p + 12);                        \
    }

  #define LOAD_F(F00, F01, F10, F11, ktn)                                   \
    {                                                                       \
      F00 = wf0[(size_t)(2 * (ktn) + 0) * 64];                              \
      F01 = wf0[(size_t)(2 * (ktn) + 1) * 64];                              \
      F10 = wf1[(size_t)(2 * (ktn) + 0) * 64];                              \
      F11 = wf1[(size_t)(2 * (ktn) + 1) * 64];                              \
    }

  #define CVT_WRITE(dst, V0, V1, V2, V3)                                    \
    {                                                                       \
      uint4 u0, u1;                                                         \
      u0.x = pk2(V0.x, V0.y); u0.y = pk2(V0.z, V0.w);                       \
      u0.z = pk2(V1.x, V1.y); u0.w = pk2(V1.z, V1.w);                       \
      u1.x = pk2(V2.x, V2.y); u1.y = pk2(V2.z, V2.w);                       \
      u1.z = pk2(V3.x, V3.y); u1.w = pk2(V3.z, V3.w);                       \
      *reinterpret_cast<uint4*>(&Alds[dst][awr])     = u0;                  \
      *reinterpret_cast<uint4*>(&Alds[dst][awr + 8]) = u1;                  \
    }

  #define COMPUTE(cur, F00, F01, F10, F11)                                  \
    {                                                                       \
      bf16x8 af0, af1, ag0, ag1;                                            \
      af0 = *reinterpret_cast<const bf16x8*>(&Alds[cur][rA0]);              \
      af1 = *reinterpret_cast<const bf16x8*>(&Alds[cur][rA1]);              \
      ag0 = *reinterpret_cast<const bf16x8*>(&Alds[cur][rA0 + 16]);         \
      ag1 = *reinterpret_cast<const bf16x8*>(&Alds[cur][rA1 + 16]);         \
      __builtin_amdgcn_s_setprio(1);                                        \
      acc[0][0] = __builtin_amdgcn_mfma_f32_32x32x16_bf16(af0, F00, acc[0][0], 0, 0, 0); \
      acc[0][1] = __builtin_amdgcn_mfma_f32_32x32x16_bf16(af0, F10, acc[0][1], 0, 0, 0); \
      acc[1][0] = __builtin_amdgcn_mfma_f32_32x32x16_bf16(af1, F00, acc[1][0], 0, 0, 0); \
      acc[1][1] = __builtin_amdgcn_mfma_f32_32x32x16_bf16(af1, F10, acc[1][1], 0, 0, 0); \
      acc[0][0] = __builtin_amdgcn_mfma_f32_32x32x16_bf16(ag0, F01, acc[0][0], 0, 0, 0); \
      acc[0][1] = __builtin_amdgcn_mfma_f32_32x32x16_bf16(ag0, F11, acc[0][1], 0, 0, 0); \
      acc[1][0] = __builtin_amdgcn_mfma_f32_32x32x16_bf16(ag1, F01, acc[1][0], 0, 0, 0); \
      acc[1][1] = __builtin_amdgcn_mfma_f32_32x32x16_bf16(ag1, F11, acc[1][1], 0, 0, 0); \
      __builtin_amdgcn_s_setprio(0);                                        \
    }

  // lgkm-only barrier: A ds_writes visible; register-destined vm loads stay in flight
  #define BAR_LGKM                                                          \
    asm volatile("s_waitcnt lgkmcnt(0)" ::: "memory");                      \
    __builtin_amdgcn_s_barrier();                                           \
    asm volatile("" ::: "memory");

  // ---- prologue: A(0) -> buf0; h(1), F(0), F(1) in flight
  LOAD_H(ha0, ha1, ha2, ha3, 0);
  CVT_WRITE(0, ha0, ha1, ha2, ha3);
  LOAD_H(hb0, hb1, hb2, hb3, 1);
  LOAD_F(fa00, fa01, fa10, fa11, 0);
  LOAD_F(fb00, fb01, fb10, fb11, 1);
  BAR_LGKM;

  // ---- main loop: kt = 0..11 in pairs
  #pragma unroll 1
  for (int kt2 = 0; kt2 < 6; ++kt2) {
    const int kt = kt2 * 2;
    // even kt: h(kt+2) -> slot a; compute buf0 (F even); reload F(kt+2) -> fa; cvt h(kt+1) -> buf1
    LOAD_H(ha0, ha1, ha2, ha3, kt + 2);
    COMPUTE(0, fa00, fa01, fa10, fa11);
    LOAD_F(fa00, fa01, fa10, fa11, kt + 2);
    CVT_WRITE(1, hb0, hb1, hb2, hb3);
    BAR_LGKM;
    // odd kt+1: h(kt+3) -> slot b; compute buf1 (F odd); reload F(kt+3) -> fb; cvt h(kt+2) -> buf0
    LOAD_H(hb0, hb1, hb2, hb3, kt + 3);
    COMPUTE(1, fb00, fb01, fb10, fb11);
    LOAD_F(fb00, fb01, fb10, fb11, kt + 3);
    CVT_WRITE(0, ha0, ha1, ha2, ha3);
    BAR_LGKM;
  }

  // kt = 12: h(14) -> a; compute buf0; F(14) -> fa; cvt h(13) -> buf1
  LOAD_H(ha0, ha1, ha2, ha3, 14);
  COMPUTE(0, fa00, fa01, fa10, fa11);
  LOAD_F(fa00, fa01, fa10, fa11, 14);
  CVT_WRITE(1, hb0, hb1, hb2, hb3);
  BAR_LGKM;

  // kt = 13: h(15) -> b; compute buf1; F(15) -> fb; cvt h(14) -> buf0
  LOAD_H(hb0, hb1, hb2, hb3, 15);
  COMPUTE(1, fb00, fb01, fb10, fb11);
  LOAD_F(fb00, fb01, fb10, fb11, 15);
  CVT_WRITE(0, ha0, ha1, ha2, ha3);
  BAR_LGKM;

  // kt = 14: compute buf0 (F(14)); cvt h(15) -> buf1
  COMPUTE(0, fa00, fa01, fa10, fa11);
  CVT_WRITE(1, hb0, hb1, hb2, hb3);
  BAR_LGKM;

  // kt = 15: compute only (F(15))
  COMPUTE(1, fb00, fb01, fb10, fb11);

  #undef LOAD_H
  #undef LOAD_F
  #undef CVT_WRITE
  #undef COMPUTE
  #undef BAR_LGKM

  // ---- epilogue: tanh + V, reduce over this block's 128 cols -> per-row partials
  float fv[2], vv[2];
  #pragma unroll
  for (int ct = 0; ct < 2; ++ct) {
    int col = q * 128 + wc * 64 + ct * 32 + l31;
    fv[ct] = first[b * NU + col];
    vv[ct] = V[col];
  }
  float part[2][16];
  #pragma unroll
  for (int rt = 0; rt < 2; ++rt) {
    #pragma unroll
    for (int r = 0; r < 16; ++r) {
      float p = 0.f;
      #pragma unroll
      for (int ct = 0; ct < 2; ++ct)
        p += vv[ct] * fast_tanh(fv[ct] + acc[rt][ct][r]);
      #pragma unroll
      for (int m = 1; m < 32; m <<= 1) p += __shfl_xor(p, m, 64);
      part[rt][r] = p;
    }
  }
  __syncthreads();
  if (wc == 0 && l31 == 0) {
    #pragma unroll
    for (int rt = 0; rt < 2; ++rt)
      #pragma unroll
      for (int r = 0; r < 16; ++r)
        scores_lds[wr * 64 + rt * 32 + (r & 3) + 8 * (r >> 2) + 4 * hi] = part[rt][r];
  }
  __syncthreads();
  if (wc == 1 && l31 == 0) {
    #pragma unroll
    for (int rt = 0; rt < 2; ++rt)
      #pragma unroll
      for (int r = 0; r < 16; ++r)
        scores_lds[wr * 64 + rt * 32 + (r & 3) + 8 * (r >> 2) + 4 * hi] += part[rt][r];
  }
  __syncthreads();
  if (tid < 256) atomicAdd(&s0[rowbase + tid], scores_lds[tid]);
}

// ---------- softmax over S per batch (in-place in d_out) + context ----------
__global__ __launch_bounds__(256) void softmax_ctx(const float* __restrict__ sp,
                                                   float* __restrict__ out) {
  const int b = blockIdx.x;
  const int t = threadIdx.x;
  float* wgt = out + NBATCH * NU + (size_t)b * SEQ;
  __shared__ float red[4];

  float v[8];
  float mx = -1e30f;
  #pragma unroll
  for (int i = 0; i < 8; ++i) { v[i] = wgt[t + i * 256]; mx = fmaxf(mx, v[i]); }
  #pragma unroll
  for (int m = 1; m < 64; m <<= 1) mx = fmaxf(mx, __shfl_xor(mx, m, 64));
  if ((t & 63) == 0) red[t >> 6] = mx;
  __syncthreads();
  mx = fmaxf(fmaxf(red[0], red[1]), fmaxf(red[2], red[3]));
  __syncthreads();

  float se = 0.f;
  #pragma unroll
  for (int i = 0; i < 8; ++i) { v[i] = __expf(v[i] - mx); se += v[i]; }
  #pragma unroll
  for (int m = 1; m < 64; m <<= 1) se += __shfl_xor(se, m, 64);
  if ((t & 63) == 0) red[t >> 6] = se;
  __syncthreads();
  se = red[0] + red[1] + red[2] + red[3];
  __syncthreads();

  const float inv = 1.0f / se;
  float sw = 0.f;
  #pragma unroll
  for (int i = 0; i < 8; ++i) { float wi = v[i] * inv; wgt[t + i * 256] = wi; sw += wi; }
  #pragma unroll
  for (int m = 1; m < 64; m <<= 1) sw += __shfl_xor(sw, m, 64);
  if ((t & 63) == 0) red[t >> 6] = sw;
  __syncthreads();
  sw = red[0] + red[1] + red[2] + red[3];

  out[b * NU + t]       = sp[b * NU + t] * sw;
  out[b * NU + t + 256] = sp[b * NU + t + 256] * sw;
}

extern "C" void kernel_launch(void* const* d_in, const int* in_sizes, int n_in,
                              void* d_out, int out_size, void* d_ws, size_t ws_size,
                              hipStream_t stream) {
  (void)in_sizes; (void)n_in; (void)out_size; (void)ws_size;
  const float* s_prev = (const float*)d_in[0];
  const float* h      = (const float*)d_in[1];
  const float* Wk     = (const float*)d_in[2];
  const float* Wb     = (const float*)d_in[3];
  const float* Uk     = (const float*)d_in[4];
  const float* Ub     = (const float*)d_in[5];
  const float* Vk     = (const float*)d_in[6];
  // d_in[7] = V_bias: softmax-shift-invariant, does not affect outputs.

  float* out   = (float*)d_out;
  float* first = (float*)d_ws;                    // 64 KB
  short* Wfrag = (short*)((char*)d_ws + 65536);   // 512 KB pre-packed B fragments
  float* s0    = out + NBATCH * NU;               // score accumulator in weights slot

  hipMemsetAsync(s0, 0, (size_t)NBATCH * SEQ * sizeof(float), stream);
  prep_all   <<< 192, 256, 0, stream>>>(Wk, s_prev, Uk, Ub, Wb, Wfrag, first);
  attn_main  <<<1024, 512, 0, stream>>>(h, Wfrag, first, Vk, s0);
  softmax_ctx<<<  32, 256, 0, stream>>>(s_prev, out);
}

// Round 15
// 157.556 us; speedup vs baseline: 1.7315x; 1.7315x over previous
//
#include <hip/hip_runtime.h>

#define NBATCH 32
#define SEQ    2048
#define NU     512
#define ASTRB  132   // A LDS row stride in BYTES (66 shorts): row starts rotate banks

typedef __attribute__((ext_vector_type(8)))  short bf16x8;
typedef __attribute__((ext_vector_type(16))) float f32x16;

__device__ __forceinline__ short bf16_rne(float f) {
  union { float f; unsigned u; } v; v.f = f;
  unsigned r = v.u + 0x7fffu + ((v.u >> 16) & 1u);
  return (short)(r >> 16);
}

__device__ __forceinline__ unsigned pk2(float lo, float hi) {
  return __builtin_amdgcn_perm(__float_as_uint(hi), __float_as_uint(lo), 0x07060302u);
}

__device__ __forceinline__ float fast_tanh(float x) {
  float ax = __builtin_fabsf(x);
  float t  = __expf(-2.0f * ax);
  float r  = (1.0f - t) / (1.0f + t);
  return x < 0.0f ? -r : r;
}

// ---------- fused prep ----------
// blocks 0..1023: WtSw unit-swizzled transpose:
//   WtSw[C*512 + t*64 + u*8 + e] = bf16(W[(t*64 + (u^(C&7))*8 + e)*512 + C])
//   (16B-unit XOR within each 64-k tile; global_load_lds stages linearly, reader
//    applies the same XOR -> B ds_read_b128 spreads 8 bank-slots, rule #21)
// blocks 1024..1087: first[b][u] = s_prev[b]@U + U_bias + W_bias
__global__ __launch_bounds__(256) void prep_all(const float* __restrict__ W,
                                                const float* __restrict__ sp,
                                                const float* __restrict__ U,
                                                const float* __restrict__ Ub,
                                                const float* __restrict__ Wb,
                                                short* __restrict__ WtSw,
                                                float* __restrict__ first) {
  __shared__ float srow[NU];
  if (blockIdx.x < 1024) {
    int idx = blockIdx.x * 256 + threadIdx.x;
    int C = idx >> 9, rem = idx & 511;
    int t = rem >> 6, u = (rem >> 3) & 7, e = rem & 7;
    int k = t * 64 + ((u ^ (C & 7)) << 3) + e;
    WtSw[idx] = bf16_rne(W[(size_t)k * NU + C]);
  } else {
    int blk = blockIdx.x - 1024;
    int b = blk >> 1, half = blk & 1, t = threadIdx.x;
    srow[t]       = sp[b * NU + t];
    srow[t + 256] = sp[b * NU + t + 256];
    __syncthreads();
    int col = half * 256 + t;
    float acc = Ub[col] + Wb[col];
    #pragma unroll 8
    for (int k = 0; k < NU; ++k) acc += srow[k] * U[(size_t)k * NU + col];
    first[b * NU + col] = acc;
  }
}

// ---------- main: 256x256 block, BK=64, counted-vmcnt dbuf, 128x64 wave tiles ----------
// 8 waves as 2 wr x 4 wc. Per-wave per K-tile: 32 MFMA (256 cyc) per barrier —
// 4x the 2-phase kernels' per-barrier MFMA work; 8 K-tiles (barriers) total.
// B via global_load_lds (pre-swizzled WtSw); A reg-staged fp32->bf16.
// Issue order A-then-B keeps B in flight across A's cvt wait (ordered vmcnt).
__global__ __launch_bounds__(512, 2) void attn_main(
    const float* __restrict__ h,      // (65536, 512) fp32
    const short* __restrict__ WtSw,   // pre-swizzled (512 x 512) bf16
    const float* __restrict__ first,  // (B, 512) incl. U_bias + W_bias
    const float* __restrict__ V,      // (512)
    float* __restrict__ s0)           // (65536) score accumulator (pre-zeroed)
{
  __shared__ short Alds[2][256 * 66];   // 33 KB each: [row][64k], stride 66 shorts
  __shared__ short Blds[2][256 * 64];   // 32 KB each: [col][8 units x 8], unit-swizzled

  const int tid  = threadIdx.x;
  const int lane = tid & 63;
  const int w    = tid >> 6;          // 0..7
  const int wr   = w >> 2, wc = w & 3;
  const int l31  = lane & 31, hi = lane >> 5;

  // XCD pairing: the 2 col-halves of a panel adjacent on one XCD
  const int bid = blockIdx.x;
  const int lb  = (bid & 7) * 64 + (bid >> 3);     // 512 = 8*64, bijective
  const int panel = lb >> 1, half = lb & 1;
  const int rowbase = panel * 256;
  const int b = rowbase >> 11;

  // ---- A staging: thread -> (row, 32-float half of the 64-k tile)
  const int arow  = tid >> 1;
  const int ahalf = tid & 1;
  const float* hA = h + (size_t)(rowbase + arow) * NU + ahalf * 32;
  const int awb   = arow * ASTRB + ahalf * 64;     // byte offset in A buffer

  // ---- B DMA: wave w covers cols [w*32, w*32+32); 4 instrs x (64 lanes x 16B)
  const short* bsrc = WtSw + (size_t)(half * 256 + w * 32 + (lane >> 3)) * NU + (lane & 7) * 8;

  #define GLOAD_B(buf, t)                                                               \
    {                                                                                   \
      _Pragma("unroll")                                                                 \
      for (int i = 0; i < 4; ++i)                                                       \
        __builtin_amdgcn_global_load_lds(                                               \
            (const __attribute__((address_space(1))) unsigned*)(bsrc + (size_t)i * 8 * NU + (t) * 64), \
            (__attribute__((address_space(3))) unsigned*)(&Blds[buf][w * 2048 + i * 512]), 16, 0, 0);  \
      asm volatile("" ::: "memory");                                                    \
    }

  // ---- compute-read bases (bytes)
  int aB[4], bB[2];
  #pragma unroll
  for (int rt = 0; rt < 4; ++rt) aB[rt] = (wr * 128 + rt * 32 + l31) * ASTRB;
  #pragma unroll
  for (int ct = 0; ct < 2; ++ct) bB[ct] = (wc * 64 + ct * 32 + l31) * 128;
  const int sw7 = l31 & 7;

  f32x16 acc[4][2];
  #pragma unroll
  for (int rt = 0; rt < 4; ++rt)
    #pragma unroll
    for (int ct = 0; ct < 2; ++ct)
      #pragma unroll
      for (int r = 0; r < 16; ++r) acc[rt][ct][r] = 0.f;

  float4 ga0, ga1, ga2, ga3, ga4, ga5, ga6, ga7;   // A slot a (32 floats)
  float4 gb0, gb1, gb2, gb3, gb4, gb5, gb6, gb7;   // A slot b

  #define LOAD_A(P0,P1,P2,P3,P4,P5,P6,P7, t)                                  \
    {                                                                         \
      const float* p = hA + (t) * 64;                                         \
      P0 = *reinterpret_cast<const float4*>(p + 0);                           \
      P1 = *reinterpret_cast<const float4*>(p + 4);                           \
      P2 = *reinterpret_cast<const float4*>(p + 8);                           \
      P3 = *reinterpret_cast<const float4*>(p + 12);                          \
      P4 = *reinterpret_cast<const float4*>(p + 16);                          \
      P5 = *reinterpret_cast<const float4*>(p + 20);                          \
      P6 = *reinterpret_cast<const float4*>(p + 24);                          \
      P7 = *reinterpret_cast<const float4*>(p + 28);                          \
    }

  #define CVT_WRITE(dst, P0,P1,P2,P3,P4,P5,P6,P7)                             \
    {                                                                         \
      char* base = reinterpret_cast<char*>(&Alds[dst][0]) + awb;              \
      uint4 u;                                                                \
      u.x = pk2(P0.x,P0.y); u.y = pk2(P0.z,P0.w);                             \
      u.z = pk2(P1.x,P1.y); u.w = pk2(P1.z,P1.w);                             \
      *reinterpret_cast<uint4*>(base + 0)  = u;                               \
      u.x = pk2(P2.x,P2.y); u.y = pk2(P2.z,P2.w);                             \
      u.z = pk2(P3.x,P3.y); u.w = pk2(P3.z,P3.w);                             \
      *reinterpret_cast<uint4*>(base + 16) = u;                               \
      u.x = pk2(P4.x,P4.y); u.y = pk2(P4.z,P4.w);                             \
      u.z = pk2(P5.x,P5.y); u.w = pk2(P5.z,P5.w);                             \
      *reinterpret_cast<uint4*>(base + 32) = u;                               \
      u.x = pk2(P6.x,P6.y); u.y = pk2(P6.z,P6.w);                             \
      u.z = pk2(P7.x,P7.y); u.w = pk2(P7.z,P7.w);                             \
      *reinterpret_cast<uint4*>(base + 48) = u;                               \
    }

  #define COMPUTE(cur)                                                        \
    {                                                                         \
      const char* ab = reinterpret_cast<const char*>(&Alds[cur][0]);          \
      const char* bb = reinterpret_cast<const char*>(&Blds[cur][0]);          \
      _Pragma("unroll")                                                       \
      for (int s = 0; s < 4; ++s) {                                           \
        const int ua = (2 * s + hi) * 16;                                     \
        const int ub = ((2 * s + hi) ^ sw7) * 16;                             \
        bf16x8 af0 = *reinterpret_cast<const bf16x8*>(ab + aB[0] + ua);       \
        bf16x8 af1 = *reinterpret_cast<const bf16x8*>(ab + aB[1] + ua);       \
        bf16x8 af2 = *reinterpret_cast<const bf16x8*>(ab + aB[2] + ua);       \
        bf16x8 af3 = *reinterpret_cast<const bf16x8*>(ab + aB[3] + ua);       \
        bf16x8 bf0 = *reinterpret_cast<const bf16x8*>(bb + bB[0] + ub);       \
        bf16x8 bf1 = *reinterpret_cast<const bf16x8*>(bb + bB[1] + ub);       \
        __builtin_amdgcn_s_setprio(1);                                        \
        acc[0][0] = __builtin_amdgcn_mfma_f32_32x32x16_bf16(af0, bf0, acc[0][0], 0, 0, 0); \
        acc[0][1] = __builtin_amdgcn_mfma_f32_32x32x16_bf16(af0, bf1, acc[0][1], 0, 0, 0); \
        acc[1][0] = __builtin_amdgcn_mfma_f32_32x32x16_bf16(af1, bf0, acc[1][0], 0, 0, 0); \
        acc[1][1] = __builtin_amdgcn_mfma_f32_32x32x16_bf16(af1, bf1, acc[1][1], 0, 0, 0); \
        acc[2][0] = __builtin_amdgcn_mfma_f32_32x32x16_bf16(af2, bf0, acc[2][0], 0, 0, 0); \
        acc[2][1] = __builtin_amdgcn_mfma_f32_32x32x16_bf16(af2, bf1, acc[2][1], 0, 0, 0); \
        acc[3][0] = __builtin_amdgcn_mfma_f32_32x32x16_bf16(af3, bf0, acc[3][0], 0, 0, 0); \
        acc[3][1] = __builtin_amdgcn_mfma_f32_32x32x16_bf16(af3, bf1, acc[3][1], 0, 0, 0); \
        __builtin_amdgcn_s_setprio(0);                                        \
      }                                                                       \
    }

  #define WAIT_VM(N) asm volatile("s_waitcnt vmcnt(" #N ")" ::: "memory");
  #define BAR_LGKM                                                            \
    asm volatile("s_waitcnt lgkmcnt(0)" ::: "memory");                        \
    __builtin_amdgcn_s_barrier();                                             \
    asm volatile("" ::: "memory");

  // ---- prologue: A(0)->buf0 via regs; B(0) DMA; A(1) in flight
  LOAD_A(ga0,ga1,ga2,ga3,ga4,ga5,ga6,ga7, 0);
  GLOAD_B(0, 0);
  CVT_WRITE(0, ga0,ga1,ga2,ga3,ga4,ga5,ga6,ga7);  // waits A(0) only (B(0) younger)
  LOAD_A(gb0,gb1,gb2,gb3,gb4,gb5,gb6,gb7, 1);
  BAR_LGKM;

  // ---- main loop: K-tiles t = 0..5 in pairs
  #pragma unroll 1
  for (int t2 = 0; t2 < 3; ++t2) {
    const int t = t2 * 2;
    // even t (cur=0): drain B(t); DMA B(t+1)->buf1; compute buf0; cvt A(t+1); load A(t+2)
    WAIT_VM(8);
    GLOAD_B(1, t + 1);
    COMPUTE(0);
    CVT_WRITE(1, gb0,gb1,gb2,gb3,gb4,gb5,gb6,gb7);   // A(t+1); auto-wait leaves B(t+1)
    LOAD_A(ga0,ga1,ga2,ga3,ga4,ga5,ga6,ga7, t + 2);
    BAR_LGKM;
    // odd t+1 (cur=1): drain B(t+1); DMA B(t+2)->buf0; compute buf1; cvt A(t+2); load A(t+3)
    WAIT_VM(8);
    GLOAD_B(0, t + 2);
    COMPUTE(1);
    CVT_WRITE(0, ga0,ga1,ga2,ga3,ga4,ga5,ga6,ga7);   // A(t+2)
    LOAD_A(gb0,gb1,gb2,gb3,gb4,gb5,gb6,gb7, t + 3);
    BAR_LGKM;
  }

  // t = 6 (cur=0): drain B(6); DMA B(7)->buf1; compute buf0; cvt A(7); no more A
  WAIT_VM(8);
  GLOAD_B(1, 7);
  COMPUTE(0);
  CVT_WRITE(1, gb0,gb1,gb2,gb3,gb4,gb5,gb6,gb7);     // A(7)
  BAR_LGKM;

  // t = 7 (cur=1): drain B(7); compute buf1
  WAIT_VM(0);
  COMPUTE(1);

  #undef GLOAD_B
  #undef LOAD_A
  #undef CVT_WRITE
  #undef COMPUTE
  #undef WAIT_VM
  #undef BAR_LGKM

  // ---- epilogue: tanh + V, reduce over wave's 64 cols (l31), atomicAdd rows
  float fv[2], vv[2];
  #pragma unroll
  for (int ct = 0; ct < 2; ++ct) {
    int col = half * 256 + wc * 64 + ct * 32 + l31;
    fv[ct] = first[b * NU + col];
    vv[ct] = V[col];
  }
  #pragma unroll
  for (int rt = 0; rt < 4; ++rt) {
    float p[16];
    #pragma unroll
    for (int r = 0; r < 16; ++r) {
      p[r] = vv[0] * fast_tanh(fv[0] + acc[rt][0][r])
           + vv[1] * fast_tanh(fv[1] + acc[rt][1][r]);
    }
    #pragma unroll
    for (int m = 1; m < 32; m <<= 1) {
      #pragma unroll
      for (int r = 0; r < 16; ++r) p[r] += __shfl_xor(p[r], m, 64);
    }
    if (l31 == 0) {
      const int rb = rowbase + wr * 128 + rt * 32 + 4 * hi;
      #pragma unroll
      for (int r = 0; r < 16; ++r)
        atomicAdd(&s0[rb + (r & 3) + 8 * (r >> 2)], p[r]);
    }
  }
}

// ---------- softmax over S per batch (in-place in d_out) + context ----------
__global__ __launch_bounds__(256) void softmax_ctx(const float* __restrict__ sp,
                                                   float* __restrict__ out) {
  const int b = blockIdx.x;
  const int t = threadIdx.x;
  float* wgt = out + NBATCH * NU + (size_t)b * SEQ;
  __shared__ float red[4];

  float v[8];
  float mx = -1e30f;
  #pragma unroll
  for (int i = 0; i < 8; ++i) { v[i] = wgt[t + i * 256]; mx = fmaxf(mx, v[i]); }
  #pragma unroll
  for (int m = 1; m < 64; m <<= 1) mx = fmaxf(mx, __shfl_xor(mx, m, 64));
  if ((t & 63) == 0) red[t >> 6] = mx;
  __syncthreads();
  mx = fmaxf(fmaxf(red[0], red[1]), fmaxf(red[2], red[3]));
  __syncthreads();

  float se = 0.f;
  #pragma unroll
  for (int i = 0; i < 8; ++i) { v[i] = __expf(v[i] - mx); se += v[i]; }
  #pragma unroll
  for (int m = 1; m < 64; m <<= 1) se += __shfl_xor(se, m, 64);
  if ((t & 63) == 0) red[t >> 6] = se;
  __syncthreads();
  se = red[0] + red[1] + red[2] + red[3];
  __syncthreads();

  const float inv = 1.0f / se;
  float sw = 0.f;
  #pragma unroll
  for (int i = 0; i < 8; ++i) { float wi = v[i] * inv; wgt[t + i * 256] = wi; sw += wi; }
  #pragma unroll
  for (int m = 1; m < 64; m <<= 1) sw += __shfl_xor(sw, m, 64);
  if ((t & 63) == 0) red[t >> 6] = sw;
  __syncthreads();
  sw = red[0] + red[1] + red[2] + red[3];

  out[b * NU + t]       = sp[b * NU + t] * sw;
  out[b * NU + t + 256] = sp[b * NU + t + 256] * sw;
}

extern "C" void kernel_launch(void* const* d_in, const int* in_sizes, int n_in,
                              void* d_out, int out_size, void* d_ws, size_t ws_size,
                              hipStream_t stream) {
  (void)in_sizes; (void)n_in; (void)out_size; (void)ws_size;
  const float* s_prev = (const float*)d_in[0];
  const float* h      = (const float*)d_in[1];
  const float* Wk     = (const float*)d_in[2];
  const float* Wb     = (const float*)d_in[3];
  const float* Uk     = (const float*)d_in[4];
  const float* Ub     = (const float*)d_in[5];
  const float* Vk     = (const float*)d_in[6];
  // d_in[7] = V_bias: softmax-shift-invariant, does not affect outputs.

  float* out   = (float*)d_out;
  float* first = (float*)d_ws;                    // 64 KB
  short* WtSw  = (short*)((char*)d_ws + 65536);   // 512 KB
  float* s0    = out + NBATCH * NU;               // score accumulator in weights slot

  hipMemsetAsync(s0, 0, (size_t)NBATCH * SEQ * sizeof(float), stream);
  prep_all   <<<1088, 256, 0, stream>>>(Wk, s_prev, Uk, Ub, Wb, WtSw, first);
  attn_main  <<< 512, 512, 0, stream>>>(h, WtSw, first, Vk, s0);
  softmax_ctx<<<  32, 256, 0, stream>>>(s_prev, out);
}

// Round 16
// 113.015 us; speedup vs baseline: 2.4139x; 1.3941x over previous
//
#include <hip/hip_runtime.h>

#define NBATCH 32
#define SEQ    2048
#define NU     512

typedef __attribute__((ext_vector_type(8))) short bf16x8;
typedef __attribute__((ext_vector_type(4))) float f32x4;

__device__ __forceinline__ short bf16_rne(float f) {
  union { float f; unsigned u; } v; v.f = f;
  unsigned r = v.u + 0x7fffu + ((v.u >> 16) & 1u);
  return (short)(r >> 16);
}

// pack bf16(lo), bf16(hi) (truncation) into one u32 via a single v_perm_b32
__device__ __forceinline__ unsigned pk2(float lo, float hi) {
  return __builtin_amdgcn_perm(__float_as_uint(hi), __float_as_uint(lo), 0x07060302u);
}

__device__ __forceinline__ float fast_tanh(float x) {
  float ax = __builtin_fabsf(x);
  float t  = __expf(-2.0f * ax);
  float r  = (1.0f - t) / (1.0f + t);
  return x < 0.0f ? -r : r;
}

// ---------- fused prep ----------
// blocks 0..1023: WtSw unit-swizzled transpose. Stored slot (C, kt, u', e), u' in 0..3
// (16B k-units within the 32-k tile), holds logical unit u'^(C&3):
//   WtSw[C*512 + kt*32 + u'*8 + e] = bf16(W[(kt*32 + ((u'^(C&3))<<3) + e)*512 + C])
// -> global_load_lds stages linearly; reader XORs the unit index -> ~conflict-free.
// blocks 1024..1087: first[b][u] = s_prev[b]@U + U_bias + W_bias
__global__ __launch_bounds__(256) void prep_all(const float* __restrict__ W,
                                                const float* __restrict__ sp,
                                                const float* __restrict__ U,
                                                const float* __restrict__ Ub,
                                                const float* __restrict__ Wb,
                                                short* __restrict__ WtSw,
                                                float* __restrict__ first) {
  __shared__ float srow[NU];
  if (blockIdx.x < 1024) {
    int idx = blockIdx.x * 256 + threadIdx.x;
    int C = idx >> 9, rem = idx & 511;
    int kt = rem >> 5, rem2 = rem & 31;
    int up = rem2 >> 3, e = rem2 & 7;
    int k = kt * 32 + ((up ^ (C & 3)) << 3) + e;
    WtSw[idx] = bf16_rne(W[(size_t)k * NU + C]);
  } else {
    int blk = blockIdx.x - 1024;
    int b = blk >> 1, half = blk & 1, t = threadIdx.x;
    srow[t]       = sp[b * NU + t];
    srow[t + 256] = sp[b * NU + t + 256];
    __syncthreads();
    int col = half * 256 + t;
    float acc = Ub[col] + Wb[col];
    #pragma unroll 8
    for (int k = 0; k < NU; ++k) acc += srow[k] * U[(size_t)k * NU + col];
    first[b * NU + col] = acc;
  }
}

// ---------- main: m97-faithful — DMA-only staging, cvt in compute phase ----------
// 128 rows x 128 cols per block, BK=32, 4 waves (64x64 tiles, 16x16x32 MFMA).
// A staged as FP32 via global_load_lds with per-lane SOURCE permutation
// (u_log = u_slot ^ (row&7)); reader XORs the same -> uniform banks.
// B staged via global_load_lds from pre-swizzled WtSw (u' = u ^ (col&3)).
// One __syncthreads per K-step (compiler's vmcnt drain completes the DMA).
__global__ __launch_bounds__(256, 3) void attn_main(
    const float* __restrict__ h,      // (65536, 512) fp32
    const short* __restrict__ WtSw,   // pre-swizzled (512 x 512) bf16
    const float* __restrict__ first,  // (B, 512) incl. U_bias + W_bias
    const float* __restrict__ V,      // (512)
    float* __restrict__ s0)           // (65536) score accumulator (pre-zeroed)
{
  __shared__ float Alds[2][128 * 32];   // fp32, 16 KB each: [row][32k], linear
  __shared__ short Blds[2][128 * 32];   // bf16,  8 KB each: [col][4 units x 8], swizzled

  const int tid  = threadIdx.x;
  const int lane = tid & 63;
  const int w    = tid >> 6;          // 0..3
  const int wr   = w >> 1, wc = w & 1;
  const int lr   = lane & 15, hi2 = lane >> 4;   // 16x16 fragment coords

  // XCD-aware remap (R4-proven, grid 2048): 4 col-groups of a panel on one XCD
  const int bid = blockIdx.x;
  const int lb  = (bid & 7) * 256 + (bid >> 3);
  const int panel = lb >> 2, q = lb & 3;
  const int rowbase = panel * 128;
  const int b = panel >> 4;

  // ---- A DMA sources: instr i (i=0..3 per wave, j = w*4+i) covers rows j*8..j*8+7.
  // lane l -> row j*8 + (l>>3), LDS unit slot (l&7); slot must hold logical unit
  // (l&7) ^ (row&7) = (l&7) ^ (l>>3).  (j*8 contributes 0 mod 8.)
  const float* srcA[4];
  #pragma unroll
  for (int i = 0; i < 4; ++i) {
    int r = (w * 4 + i) * 8 + (lane >> 3);
    srcA[i] = h + (size_t)(rowbase + r) * NU + (((lane & 7) ^ (lane >> 3)) << 2);
  }
  // ---- B DMA sources: instr i (i=0..1, j = w*2+i) covers cols j*16..+16.
  const short* srcB[2];
  #pragma unroll
  for (int i = 0; i < 2; ++i) {
    int c = (w * 2 + i) * 16 + (lane >> 2);
    srcB[i] = WtSw + (size_t)(q * 128 + c) * NU + (lane & 3) * 8;
  }

  #define GLOAD(buf, kt)                                                               \
    {                                                                                  \
      _Pragma("unroll")                                                                \
      for (int i = 0; i < 4; ++i)                                                      \
        __builtin_amdgcn_global_load_lds(                                              \
            (const __attribute__((address_space(1))) unsigned*)(srcA[i] + (kt) * 32),  \
            (__attribute__((address_space(3))) unsigned*)(&Alds[buf][(w * 4 + i) * 256]), 16, 0, 0); \
      _Pragma("unroll")                                                                \
      for (int i = 0; i < 2; ++i)                                                      \
        __builtin_amdgcn_global_load_lds(                                              \
            (const __attribute__((address_space(1))) unsigned*)(srcB[i] + (kt) * 32),  \
            (__attribute__((address_space(3))) unsigned*)(&Blds[buf][(w * 2 + i) * 512]), 16, 0, 0); \
      asm volatile("" ::: "memory");                                                   \
    }

  // ---- compute-read byte offsets (all loop-invariant)
  // A: row = wr*64 + rc*16 + lr; logical unit v = 2*hi2 + jj; slot = v ^ (lr&7)
  int aoff[4][2];
  #pragma unroll
  for (int rc = 0; rc < 4; ++rc)
    #pragma unroll
    for (int jj = 0; jj < 2; ++jj)
      aoff[rc][jj] = (wr * 64 + rc * 16 + lr) * 128 + (((2 * hi2 + jj) ^ (lr & 7)) << 4);
  // B: col = wc*64 + cc*16 + lr; logical unit hi2; slot = hi2 ^ (lr&3)
  int boff[4];
  #pragma unroll
  for (int cc = 0; cc < 4; ++cc)
    boff[cc] = (wc * 64 + cc * 16 + lr) * 64 + ((hi2 ^ (lr & 3)) << 4);

  f32x4 acc[4][4];
  #pragma unroll
  for (int rc = 0; rc < 4; ++rc)
    #pragma unroll
    for (int cc = 0; cc < 4; ++cc)
      acc[rc][cc] = (f32x4){0.f, 0.f, 0.f, 0.f};

  #define COMPUTE(cur)                                                        \
    {                                                                         \
      const char* ab = reinterpret_cast<const char*>(&Alds[cur][0]);          \
      const char* bb = reinterpret_cast<const char*>(&Blds[cur][0]);          \
      bf16x8 af[4], bf[4];                                                    \
      _Pragma("unroll")                                                       \
      for (int rc = 0; rc < 4; ++rc) {                                        \
        float4 x0 = *reinterpret_cast<const float4*>(ab + aoff[rc][0]);       \
        float4 x1 = *reinterpret_cast<const float4*>(ab + aoff[rc][1]);       \
        uint4 u;                                                              \
        u.x = pk2(x0.x, x0.y); u.y = pk2(x0.z, x0.w);                         \
        u.z = pk2(x1.x, x1.y); u.w = pk2(x1.z, x1.w);                         \
        af[rc] = *reinterpret_cast<bf16x8*>(&u);                              \
      }                                                                       \
      _Pragma("unroll")                                                       \
      for (int cc = 0; cc < 4; ++cc)                                          \
        bf[cc] = *reinterpret_cast<const bf16x8*>(bb + boff[cc]);             \
      _Pragma("unroll")                                                       \
      for (int rc = 0; rc < 4; ++rc)                                          \
        _Pragma("unroll")                                                     \
        for (int cc = 0; cc < 4; ++cc)                                        \
          acc[rc][cc] = __builtin_amdgcn_mfma_f32_16x16x32_bf16(af[rc], bf[cc], acc[rc][cc], 0, 0, 0); \
    }

  // ---- prologue: stage K-tile 0
  GLOAD(0, 0);
  __syncthreads();

  // ---- main loop: 16 K-steps, m97 2-phase skeleton
  #pragma unroll 1
  for (int kt = 0; kt < 15; ++kt) {
    GLOAD(kt & 1 ? 0 : 1, kt + 1);   // DMA next tile into the other buffer
    COMPUTE(kt & 1);
    __syncthreads();                  // compiler drains vmcnt -> next tile ready
  }
  COMPUTE(1);                         // kt = 15 (buf 1), no prefetch

  #undef GLOAD
  #undef COMPUTE

  // ---- epilogue: tanh + V, reduce over wave's 64 cols, atomicAdd rows
  float fv[4], vv[4];
  #pragma unroll
  for (int cc = 0; cc < 4; ++cc) {
    int col = q * 128 + wc * 64 + cc * 16 + lr;
    fv[cc] = first[b * NU + col];
    vv[cc] = V[col];
  }
  #pragma unroll
  for (int rc = 0; rc < 4; ++rc) {
    f32x4 p;
    #pragma unroll
    for (int r = 0; r < 4; ++r) {
      float s = 0.f;
      #pragma unroll
      for (int cc = 0; cc < 4; ++cc)
        s += vv[cc] * fast_tanh(fv[cc] + acc[rc][cc][r]);
      p[r] = s;
    }
    #pragma unroll
    for (int m = 1; m < 16; m <<= 1) {
      #pragma unroll
      for (int r = 0; r < 4; ++r) p[r] += __shfl_xor(p[r], m, 64);
    }
    if (lr == 0) {
      // C layout 16x16: row = hi2*4 + r within the (wr,rc) tile
      const int rbase = rowbase + wr * 64 + rc * 16 + hi2 * 4;
      #pragma unroll
      for (int r = 0; r < 4; ++r) atomicAdd(&s0[rbase + r], p[r]);
    }
  }
}

// ---------- softmax over S per batch (in-place in d_out) + context ----------
__global__ __launch_bounds__(256) void softmax_ctx(const float* __restrict__ sp,
                                                   float* __restrict__ out) {
  const int b = blockIdx.x;
  const int t = threadIdx.x;
  float* wgt = out + NBATCH * NU + (size_t)b * SEQ;
  __shared__ float red[4];

  float v[8];
  float mx = -1e30f;
  #pragma unroll
  for (int i = 0; i < 8; ++i) { v[i] = wgt[t + i * 256]; mx = fmaxf(mx, v[i]); }
  #pragma unroll
  for (int m = 1; m < 64; m <<= 1) mx = fmaxf(mx, __shfl_xor(mx, m, 64));
  if ((t & 63) == 0) red[t >> 6] = mx;
  __syncthreads();
  mx = fmaxf(fmaxf(red[0], red[1]), fmaxf(red[2], red[3]));
  __syncthreads();

  float se = 0.f;
  #pragma unroll
  for (int i = 0; i < 8; ++i) { v[i] = __expf(v[i] - mx); se += v[i]; }
  #pragma unroll
  for (int m = 1; m < 64; m <<= 1) se += __shfl_xor(se, m, 64);
  if ((t & 63) == 0) red[t >> 6] = se;
  __syncthreads();
  se = red[0] + red[1] + red[2] + red[3];
  __syncthreads();

  const float inv = 1.0f / se;
  float sw = 0.f;
  #pragma unroll
  for (int i = 0; i < 8; ++i) { float wi = v[i] * inv; wgt[t + i * 256] = wi; sw += wi; }
  #pragma unroll
  for (int m = 1; m < 64; m <<= 1) sw += __shfl_xor(sw, m, 64);
  if ((t & 63) == 0) red[t >> 6] = sw;
  __syncthreads();
  sw = red[0] + red[1] + red[2] + red[3];

  out[b * NU + t]       = sp[b * NU + t] * sw;
  out[b * NU + t + 256] = sp[b * NU + t + 256] * sw;
}

extern "C" void kernel_launch(void* const* d_in, const int* in_sizes, int n_in,
                              void* d_out, int out_size, void* d_ws, size_t ws_size,
                              hipStream_t stream) {
  (void)in_sizes; (void)n_in; (void)out_size; (void)ws_size;
  const float* s_prev = (const float*)d_in[0];
  const float* h      = (const float*)d_in[1];
  const float* Wk     = (const float*)d_in[2];
  const float* Wb     = (const float*)d_in[3];
  const float* Uk     = (const float*)d_in[4];
  const float* Ub     = (const float*)d_in[5];
  const float* Vk     = (const float*)d_in[6];
  // d_in[7] = V_bias: softmax-shift-invariant, does not affect outputs.

  float* out   = (float*)d_out;
  float* first = (float*)d_ws;                    // 64 KB
  short* WtSw  = (short*)((char*)d_ws + 65536);   // 512 KB
  float* s0    = out + NBATCH * NU;               // score accumulator in weights slot

  hipMemsetAsync(s0, 0, (size_t)NBATCH * SEQ * sizeof(float), stream);
  prep_all   <<<1088, 256, 0, stream>>>(Wk, s_prev, Uk, Ub, Wb, WtSw, first);
  attn_main  <<<2048, 256, 0, stream>>>(h, WtSw, first, Vk, s0);
  softmax_ctx<<<  32, 256, 0, stream>>>(s_prev, out);
}

// Round 17
// 102.318 us; speedup vs baseline: 2.6663x; 1.1045x over previous
//
#include <hip/hip_runtime.h>

#define NBATCH 32
#define SEQ    2048
#define NU     512

typedef __attribute__((ext_vector_type(8))) short bf16x8;
typedef __attribute__((ext_vector_type(4))) float f32x4;

__device__ __forceinline__ short bf16_rne(float f) {
  union { float f; unsigned u; } v; v.f = f;
  unsigned r = v.u + 0x7fffu + ((v.u >> 16) & 1u);
  return (short)(r >> 16);
}

__device__ __forceinline__ unsigned pk2(float lo, float hi) {
  return __builtin_amdgcn_perm(__float_as_uint(hi), __float_as_uint(lo), 0x07060302u);
}

__device__ __forceinline__ float fast_tanh(float x) {
  float ax = __builtin_fabsf(x);
  float t  = __expf(-2.0f * ax);
  float r  = (1.0f - t) / (1.0f + t);
  return x < 0.0f ? -r : r;
}

// ---------- fused prep ----------
// blocks 0..1023: WtSw 8-unit-XOR pre-swizzled transpose (BK=64 tiles):
//   WtSw[C*512 + t*64 + u'*8 + e] = bf16(W[(t*64 + ((u'^(C&7))<<3) + e)*512 + C])
//   global_load_lds stages linearly; reader XORs unit with (col&7) -> conflict-free.
// blocks 1024..1087: first[b][u] = s_prev[b]@U + U_bias + W_bias
__global__ __launch_bounds__(256) void prep_all(const float* __restrict__ W,
                                                const float* __restrict__ sp,
                                                const float* __restrict__ U,
                                                const float* __restrict__ Ub,
                                                const float* __restrict__ Wb,
                                                short* __restrict__ WtSw,
                                                float* __restrict__ first) {
  __shared__ float srow[NU];
  if (blockIdx.x < 1024) {
    int idx = blockIdx.x * 256 + threadIdx.x;
    int C = idx >> 9, rem = idx & 511;
    int t = rem >> 6, up = (rem >> 3) & 7, e = rem & 7;
    int k = t * 64 + ((up ^ (C & 7)) << 3) + e;
    WtSw[idx] = bf16_rne(W[(size_t)k * NU + C]);
  } else {
    int blk = blockIdx.x - 1024;
    int b = blk >> 1, half = blk & 1, t = threadIdx.x;
    srow[t]       = sp[b * NU + t];
    srow[t + 256] = sp[b * NU + t + 256];
    __syncthreads();
    int col = half * 256 + t;
    float acc = Ub[col] + Wb[col];
    #pragma unroll 8
    for (int k = 0; k < NU; ++k) acc += srow[k] * U[(size_t)k * NU + col];
    first[b * NU + col] = acc;
  }
}

// ---------- main: m201-style 8-phase schedule, 256x256 tile, BK=64 ----------
// 8 waves (2M x 4N), wave tile 128x64, acc[8][4] f32x4. Per phase: {ds-read
// subtile || stage one half-tile of K-tile t+1 || barrier || setprio+16 MFMA ||
// barrier}. ONE vmcnt(0)+lgkmcnt(0) per K-tile, placed AFTER Q11's MFMA
// (loads are 4+ phases old there -> free). A-frags reused across phase pairs.
__global__ __launch_bounds__(512, 2) void attn8(
    const float* __restrict__ h,      // (65536, 512) fp32
    const short* __restrict__ WtSw,   // pre-swizzled (512 x 512) bf16
    const float* __restrict__ first,  // (B, 512) incl. U_bias + W_bias
    const float* __restrict__ V,      // (512)
    float* __restrict__ s0)           // (65536) score accumulator (pre-zeroed)
{
  __shared__ short Alds[2][256 * 64];   // 32 KB each: [row][8 units x 8], swizzled
  __shared__ short Blds[2][256 * 64];   // 32 KB each: [col][8 units x 8], swizzled

  const int tid  = threadIdx.x;
  const int lane = tid & 63;
  const int w    = tid >> 6;            // 0..7
  const int wr   = w >> 2, wc = w & 3;  // 2M x 4N
  const int lr   = lane & 15, hi2 = lane >> 4;

  // XCD pairing: both halves of a panel adjacent on one XCD
  const int bid = blockIdx.x;
  const int lb  = (bid & 7) * 64 + (bid >> 3);   // 512 = 8*64, bijective
  const int panel = lb >> 1, half = lb & 1;
  const int rowbase = panel * 256;
  const int b = panel >> 3;

  // ---- staging bases
  const float* hstage = h + (size_t)(rowbase + (tid >> 2)) * NU + (tid & 3) * 16;
  const int rr = tid >> 2, u0 = (tid & 3) * 2;
  const int wby0 = rr * 128 + ((u0 ^ (rr & 7)) << 4);        // A write byte, unit u0
  const int wby1 = rr * 128 + (((u0 | 1) ^ (rr & 7)) << 4);  // unit u0+1
  const short* wsrc = WtSw + (size_t)(half * 256 + w * 8 + (lane >> 3)) * NU + (lane & 7) * 8;

  // ---- compute-read offsets (bytes)
  int abase[8], bbase[4], s16[2];
  #pragma unroll
  for (int j = 0; j < 8; ++j) abase[j] = (wr * 128 + j * 16 + lr) * 128;
  #pragma unroll
  for (int j = 0; j < 4; ++j) bbase[j] = (wc * 64 + j * 16 + lr) * 128;
  #pragma unroll
  for (int ks = 0; ks < 2; ++ks) s16[ks] = ((ks * 4 + hi2) ^ (lr & 7)) << 4;

  f32x4 acc[8][4];
  #pragma unroll
  for (int mf = 0; mf < 8; ++mf)
    #pragma unroll
    for (int nf = 0; nf < 4; ++nf)
      acc[mf][nf] = (f32x4){0.f, 0.f, 0.f, 0.f};

  float4 ga0, ga1, ga2, ga3;   // A-half0 stage regs
  float4 gb0, gb1, gb2, gb3;   // A-half1 stage regs

  #define STAGEB(nxt, t1, bh)                                                          \
    {                                                                                  \
      _Pragma("unroll")                                                                \
      for (int i = 0; i < 2; ++i)                                                      \
        __builtin_amdgcn_global_load_lds(                                              \
            (const __attribute__((address_space(1))) unsigned*)                        \
                (wsrc + (size_t)((bh) * 128 + i * 64) * NU + (t1) * 64),               \
            (__attribute__((address_space(3))) unsigned*)                              \
                (&Blds[nxt][(bh) * 8192 + i * 4096 + w * 512]), 16, 0, 0);             \
    }

  #define ISSA(G0, G1, G2, G3, t1, ah)                                                 \
    {                                                                                  \
      const float* p = hstage + (size_t)(ah) * 128 * NU + (t1) * 64;                   \
      G0 = *reinterpret_cast<const float4*>(p + 0);                                    \
      G1 = *reinterpret_cast<const float4*>(p + 4);                                    \
      G2 = *reinterpret_cast<const float4*>(p + 8);                                    \
      G3 = *reinterpret_cast<const float4*>(p + 12);                                   \
    }

  #define CVTW(nxt, ah, G0, G1, G2, G3)                                                \
    {                                                                                  \
      char* base = reinterpret_cast<char*>(&Alds[nxt][0]) + (ah) * 16384;              \
      uint4 ua, ub;                                                                    \
      ua.x = pk2(G0.x, G0.y); ua.y = pk2(G0.z, G0.w);                                  \
      ua.z = pk2(G1.x, G1.y); ua.w = pk2(G1.z, G1.w);                                  \
      ub.x = pk2(G2.x, G2.y); ub.y = pk2(G2.z, G2.w);                                  \
      ub.z = pk2(G3.x, G3.y); ub.w = pk2(G3.z, G3.w);                                  \
      *reinterpret_cast<uint4*>(base + wby0) = ua;                                     \
      *reinterpret_cast<uint4*>(base + wby1) = ub;                                     \
    }

  #define READ_A(mh, cur)                                                              \
    _Pragma("unroll")                                                                  \
    for (int mi = 0; mi < 4; ++mi)                                                     \
      _Pragma("unroll")                                                                \
      for (int ks = 0; ks < 2; ++ks)                                                   \
        af[mi][ks] = *reinterpret_cast<const bf16x8*>(                                 \
            reinterpret_cast<const char*>(&Alds[cur][0]) + abase[(mh) * 4 + mi] + s16[ks]);

  #define READ_B(nh, cur)                                                              \
    _Pragma("unroll")                                                                  \
    for (int ni = 0; ni < 2; ++ni)                                                     \
      _Pragma("unroll")                                                                \
      for (int ks = 0; ks < 2; ++ks)                                                   \
        bfq[ni][ks] = *reinterpret_cast<const bf16x8*>(                                \
            reinterpret_cast<const char*>(&Blds[cur][0]) + bbase[(nh) * 2 + ni] + s16[ks]);

  #define MFMAQ(mh, nh)                                                                \
    __builtin_amdgcn_s_setprio(1);                                                     \
    _Pragma("unroll")                                                                  \
    for (int ks = 0; ks < 2; ++ks)                                                     \
      _Pragma("unroll")                                                                \
      for (int mi = 0; mi < 4; ++mi)                                                   \
        _Pragma("unroll")                                                              \
        for (int ni = 0; ni < 2; ++ni)                                                 \
          acc[(mh) * 4 + mi][(nh) * 2 + ni] = __builtin_amdgcn_mfma_f32_16x16x32_bf16( \
              af[mi][ks], bfq[ni][ks], acc[(mh) * 4 + mi][(nh) * 2 + ni], 0, 0, 0);    \
    __builtin_amdgcn_s_setprio(0);

  #define BAR                                                                          \
    asm volatile("" ::: "memory");                                                     \
    __builtin_amdgcn_s_barrier();                                                      \
    asm volatile("" ::: "memory");

  // ---- prologue: stage K-tile 0 into buf 0
  STAGEB(0, 0, 0); STAGEB(0, 0, 1);
  ISSA(ga0, ga1, ga2, ga3, 0, 0);
  CVTW(0, 0, ga0, ga1, ga2, ga3);
  ISSA(gb0, gb1, gb2, gb3, 0, 1);
  CVTW(0, 1, gb0, gb1, gb2, gb3);
  asm volatile("s_waitcnt vmcnt(0) lgkmcnt(0)" ::: "memory");
  __builtin_amdgcn_s_barrier();
  asm volatile("" ::: "memory");

  // ---- main loop: K-tiles t = 0..6, staging t+1
  #pragma unroll 1
  for (int t = 0; t < 7; ++t) {
    const int cur = t & 1, nxt = cur ^ 1;
    bf16x8 af[4][2], bfq[2][2];
    // p0: Q(0,0); stage B-half0 DMA + issue A-half0 loads
    READ_A(0, cur); READ_B(0, cur);
    STAGEB(nxt, t + 1, 0);
    ISSA(ga0, ga1, ga2, ga3, t + 1, 0);
    BAR; MFMAQ(0, 0); BAR;
    // p1: Q(0,1) (af reused); stage B-half1 DMA + issue A-half1 loads
    READ_B(1, cur);
    STAGEB(nxt, t + 1, 1);
    ISSA(gb0, gb1, gb2, gb3, t + 1, 1);
    BAR; MFMAQ(0, 1); BAR;
    // p2: Q(1,0); cvt+write A-half0
    READ_A(1, cur); READ_B(0, cur);
    CVTW(nxt, 0, ga0, ga1, ga2, ga3);
    BAR; MFMAQ(1, 0); BAR;
    // p3: Q(1,1) (af reused); cvt+write A-half1; K-tile boundary wait after MFMA
    READ_B(1, cur);
    CVTW(nxt, 1, gb0, gb1, gb2, gb3);
    BAR; MFMAQ(1, 1);
    asm volatile("s_waitcnt vmcnt(0) lgkmcnt(0)" ::: "memory");
    BAR;
  }

  // ---- last K-tile (t = 7, buf 1): compute only
  {
    bf16x8 af[4][2], bfq[2][2];
    READ_A(0, 1); READ_B(0, 1);
    BAR; MFMAQ(0, 0); BAR;
    READ_B(1, 1);
    BAR; MFMAQ(0, 1); BAR;
    READ_A(1, 1); READ_B(0, 1);
    BAR; MFMAQ(1, 0); BAR;
    READ_B(1, 1);
    BAR; MFMAQ(1, 1);
  }

  #undef STAGEB
  #undef ISSA
  #undef CVTW
  #undef READ_A
  #undef READ_B
  #undef MFMAQ
  #undef BAR

  // ---- epilogue: tanh + V, reduce over wave's 64 cols, atomicAdd rows
  float fv[4], vv[4];
  #pragma unroll
  for (int nf = 0; nf < 4; ++nf) {
    int col = half * 256 + wc * 64 + nf * 16 + lr;
    fv[nf] = first[b * NU + col];
    vv[nf] = V[col];
  }
  #pragma unroll
  for (int mf = 0; mf < 8; ++mf) {
    f32x4 p;
    #pragma unroll
    for (int r = 0; r < 4; ++r) {
      float s = 0.f;
      #pragma unroll
      for (int nf = 0; nf < 4; ++nf)
        s += vv[nf] * fast_tanh(fv[nf] + acc[mf][nf][r]);
      p[r] = s;
    }
    #pragma unroll
    for (int m = 1; m < 16; m <<= 1) {
      #pragma unroll
      for (int r = 0; r < 4; ++r) p[r] += __shfl_xor(p[r], m, 64);
    }
    if (lr == 0) {
      const int rbase = rowbase + wr * 128 + mf * 16 + hi2 * 4;
      #pragma unroll
      for (int r = 0; r < 4; ++r) atomicAdd(&s0[rbase + r], p[r]);
    }
  }
}

// ---------- softmax over S per batch (in-place in d_out) + context ----------
__global__ __launch_bounds__(256) void softmax_ctx(const float* __restrict__ sp,
                                                   float* __restrict__ out) {
  const int b = blockIdx.x;
  const int t = threadIdx.x;
  float* wgt = out + NBATCH * NU + (size_t)b * SEQ;
  __shared__ float red[4];

  float v[8];
  float mx = -1e30f;
  #pragma unroll
  for (int i = 0; i < 8; ++i) { v[i] = wgt[t + i * 256]; mx = fmaxf(mx, v[i]); }
  #pragma unroll
  for (int m = 1; m < 64; m <<= 1) mx = fmaxf(mx, __shfl_xor(mx, m, 64));
  if ((t & 63) == 0) red[t >> 6] = mx;
  __syncthreads();
  mx = fmaxf(fmaxf(red[0], red[1]), fmaxf(red[2], red[3]));
  __syncthreads();

  float se = 0.f;
  #pragma unroll
  for (int i = 0; i < 8; ++i) { v[i] = __expf(v[i] - mx); se += v[i]; }
  #pragma unroll
  for (int m = 1; m < 64; m <<= 1) se += __shfl_xor(se, m, 64);
  if ((t & 63) == 0) red[t >> 6] = se;
  __syncthreads();
  se = red[0] + red[1] + red[2] + red[3];
  __syncthreads();

  const float inv = 1.0f / se;
  float sw = 0.f;
  #pragma unroll
  for (int i = 0; i < 8; ++i) { float wi = v[i] * inv; wgt[t + i * 256] = wi; sw += wi; }
  #pragma unroll
  for (int m = 1; m < 64; m <<= 1) sw += __shfl_xor(sw, m, 64);
  if ((t & 63) == 0) red[t >> 6] = sw;
  __syncthreads();
  sw = red[0] + red[1] + red[2] + red[3];

  out[b * NU + t]       = sp[b * NU + t] * sw;
  out[b * NU + t + 256] = sp[b * NU + t + 256] * sw;
}

extern "C" void kernel_launch(void* const* d_in, const int* in_sizes, int n_in,
                              void* d_out, int out_size, void* d_ws, size_t ws_size,
                              hipStream_t stream) {
  (void)in_sizes; (void)n_in; (void)out_size; (void)ws_size;
  const float* s_prev = (const float*)d_in[0];
  const float* h      = (const float*)d_in[1];
  const float* Wk     = (const float*)d_in[2];
  const float* Wb     = (const float*)d_in[3];
  const float* Uk     = (const float*)d_in[4];
  const float* Ub     = (const float*)d_in[5];
  const float* Vk     = (const float*)d_in[6];
  // d_in[7] = V_bias: softmax-shift-invariant, does not affect outputs.

  float* out   = (float*)d_out;
  float* first = (float*)d_ws;                    // 64 KB
  short* WtSw  = (short*)((char*)d_ws + 65536);   // 512 KB
  float* s0    = out + NBATCH * NU;               // score accumulator in weights slot

  hipMemsetAsync(s0, 0, (size_t)NBATCH * SEQ * sizeof(float), stream);
  prep_all   <<<1088, 256, 0, stream>>>(Wk, s_prev, Uk, Ub, Wb, WtSw, first);
  attn8      <<< 512, 512, 0, stream>>>(h, WtSw, first, Vk, s0);
  softmax_ctx<<<  32, 256, 0, stream>>>(s_prev, out);
}